// Round 1
// baseline (6771.976 us; speedup 1.0000x reference)
//
#include <hip/hip_runtime.h>
#include <math.h>

#define B_ 4
#define CIN_ 32
#define HID_ 32
#define T_ 31
#define H_ 96
#define W_ 96
#define SP_ (H_*W_)
#define OC_ 64
#define NTAP_ 27

// ---------------------------------------------------------------------------
// Kernel 0: reorder conv weights  w[oc][cin][27] -> wr[g][tap][cin][8]
// group g (0..7) covers oc {4g..4g+3} (Z) and {32+4g..32+4g+3} (F).
// Layout makes the conv inner loop read 256 consecutive floats per tap with a
// wave-uniform address -> compiler emits s_load (SGPR broadcast weights).
// ---------------------------------------------------------------------------
__global__ __launch_bounds__(256) void reorder_w_kernel(
    const float* __restrict__ w, float* __restrict__ wr) {
  int idx = blockIdx.x * 256 + threadIdx.x;
  const int total = 8 * NTAP_ * CIN_ * 8;  // 55296
  if (idx >= total) return;
  int o8  = idx & 7;
  int cin = (idx >> 3) & 31;
  int rest = idx >> 8;             // g*27 + tap
  int tap = rest % NTAP_;
  int g   = rest / NTAP_;
  int oc = (o8 < 4) ? (g * 4 + o8) : (HID_ + g * 4 + (o8 - 4));
  wr[idx] = w[(oc * CIN_ + cin) * NTAP_ + tap];
}

// ---------------------------------------------------------------------------
// Kernel 1: fused Conv3d + bias + tanh/sigmoid + time recurrence.
// Block = 128 threads = 16x8 spatial tile. Grid = (72 tiles, 8 groups, 4 batch).
// LDS ring of 3 time slices, full 32 cin, 10x19 (haloed, padded) each.
// Each thread owns one pixel; 8 accumulators (4 Z + 4 F channels); h state in
// registers across t. Writes h to d_out [B,32,31,96,96].
// ---------------------------------------------------------------------------
#define TXD 16
#define TYD 8
#define NTHR 128
#define SLICE_F (CIN_ * 10 * 19)   // 6080 floats per slice

__global__ __launch_bounds__(NTHR) void conv_rec_kernel(
    const float* __restrict__ in, const float* __restrict__ wr,
    const float* __restrict__ bias, float* __restrict__ out) {
  __shared__ float in_s[3 * SLICE_F];   // 71.25 KB

  const int tid = threadIdx.x;
  const int tile = blockIdx.x;          // 0..71
  const int g = blockIdx.y;             // 0..7
  const int b = blockIdx.z;             // 0..3
  const int x0 = (tile % 6) * TXD;
  const int y0 = (tile / 6) * TYD;
  const int tx = tid & 15;
  const int ty = tid >> 4;

  auto load_slice = [&](int ts, int slot) {
    float* dst = in_s + slot * SLICE_F;
    for (int e = tid; e < CIN_ * 180; e += NTHR) {  // 5760 elems, 45 iters
      int xx = e % 18;
      int r = e / 18;
      int yy = r % 10;
      int cin = r / 10;
      int gy = y0 - 1 + yy;
      int gx = x0 - 1 + xx;
      float v = 0.f;
      if (ts >= 0 && ts < T_ && (unsigned)gy < (unsigned)H_ &&
          (unsigned)gx < (unsigned)W_)
        v = in[((b * CIN_ + cin) * T_ + ts) * SP_ + gy * W_ + gx];
      dst[cin * 190 + yy * 19 + xx] = v;
    }
  };

  float bz[4], bf[4];
#pragma unroll
  for (int j = 0; j < 4; ++j) {
    bz[j] = bias[g * 4 + j];
    bf[j] = bias[HID_ + g * 4 + j];
  }

  // prologue: slice -1 (zeros) -> slot 2, slice 0 -> slot 0
  load_slice(-1, 2);
  load_slice(0, 0);

  float h[4] = {0.f, 0.f, 0.f, 0.f};

  for (int t = 0; t < T_; ++t) {
    load_slice(t + 1, (t + 1) % 3);   // zeros if t+1 == 31
    __syncthreads();

    float acc[8];
#pragma unroll
    for (int j = 0; j < 4; ++j) { acc[j] = bz[j]; acc[4 + j] = bf[j]; }

#pragma unroll 1
    for (int kd = 0; kd < 3; ++kd) {
      const int slot = (t + 2 + kd) % 3;   // slice t-1+kd
      const float* sbase = in_s + slot * SLICE_F + ty * 19 + tx;
      const float* wk = wr + (g * NTAP_ + kd * 9) * (CIN_ * 8);
#pragma unroll 1
      for (int kh = 0; kh < 3; ++kh) {
#pragma unroll
        for (int kw = 0; kw < 3; ++kw) {
          const float* wp = wk + (kh * 3 + kw) * (CIN_ * 8);
          const float* ip = sbase + kh * 19 + kw;
#pragma unroll
          for (int ci = 0; ci < CIN_; ++ci) {
            float iv = ip[ci * 190];
#pragma unroll
            for (int o = 0; o < 8; ++o)
              acc[o] += wp[ci * 8 + o] * iv;
          }
        }
      }
    }

#pragma unroll
    for (int j = 0; j < 4; ++j) {
      float z = tanhf(acc[j]);
      float f = 1.f / (1.f + __expf(-acc[4 + j]));
      h[j] = f * h[j] + (1.f - f) * z;
      out[((b * HID_ + g * 4 + j) * T_ + t) * SP_ + (y0 + ty) * W_ +
          (x0 + tx)] = h[j];
    }
    __syncthreads();   // compute done before ring slot is overwritten
  }
}

// ---------------------------------------------------------------------------
// Kernel 2: per-pixel channel attention, in-place on d_out.
// Block = 128 threads (2 waves), 8 pixels (x0..x0+7 of one row y, batch b).
// qh staged in LDS [8][33][33] (pitch-padded, t=31 zero pad). Each wave does
// 4 pixels: scores via lane=(d, c-half), softmax over c via shfl_xor(32),
// attn to LDS, then P phase with lane=(c, t-half). Result written back to LDS
// and cooperatively stored (coalesced).
// ---------------------------------------------------------------------------
#define PIT 33
#define PSTRIDE 1089   // 33*33

__global__ __launch_bounds__(128) void attn_kernel(
    float* __restrict__ out, const float* __restrict__ gamma) {
  __shared__ float qh_s[8 * PSTRIDE];       // 34.8 KB
  __shared__ float attn_s[2 * 32 * PIT];    // 8.4 KB

  const int tid = threadIdx.x;
  const int x0 = blockIdx.x * 8;
  const int y = blockIdx.y;
  const int b = blockIdx.z;

  // stage h -> LDS (t padded to 32 with zeros)
  for (int e = tid; e < 8 * 1024; e += 128) {
    int xi = e & 7;
    int ct = e >> 3;
    int t = ct & 31;
    int c = ct >> 5;
    float v = 0.f;
    if (t < T_)
      v = out[((b * HID_ + c) * T_ + t) * SP_ + y * W_ + x0 + xi];
    qh_s[xi * PSTRIDE + c * PIT + t] = v;
  }
  __syncthreads();

  const int wv = tid >> 6;
  const int lane = tid & 63;
  const float gm = gamma[0];

  for (int pp = 0; pp < 4; ++pp) {
    const int p = wv * 4 + pp;
    float* qs = qh_s + p * PSTRIDE;
    float* as = attn_s + wv * (32 * PIT);

    {  // scores + softmax(axis=c) ; lane holds (d = lane&31, chalf = lane>>5)
      const int d = lane & 31;
      const int ch = lane >> 5;
      float qd[T_];
#pragma unroll
      for (int t = 0; t < T_; ++t) qd[t] = qs[d * PIT + t];
      float s[16];
#pragma unroll
      for (int i = 0; i < 16; ++i) s[i] = 0.f;
#pragma unroll
      for (int t = 0; t < T_; ++t) {
#pragma unroll
        for (int i = 0; i < 16; ++i)
          s[i] += qs[(ch * 16 + i) * PIT + t] * qd[t];
      }
      float m = s[0];
#pragma unroll
      for (int i = 1; i < 16; ++i) m = fmaxf(m, s[i]);
      m = fmaxf(m, __shfl_xor(m, 32));
      float sum = 0.f;
#pragma unroll
      for (int i = 0; i < 16; ++i) { s[i] = __expf(s[i] - m); sum += s[i]; }
      sum += __shfl_xor(sum, 32);
      const float sc = 0.17677669529663688f / sum;  // (1/sqrt(32)) / denom
#pragma unroll
      for (int i = 0; i < 16; ++i) as[(ch * 16 + i) * PIT + d] = s[i] * sc;
    }
    __syncthreads();
    {  // ah = attn @ qh ; lane holds (c = lane&31, thalf = lane>>5)
      const int c = lane & 31;
      const int th = lane >> 5;
      float ah[16];
#pragma unroll
      for (int j = 0; j < 16; ++j) ah[j] = 0.f;
#pragma unroll
      for (int dd = 0; dd < 32; ++dd) {
        float a = as[c * PIT + dd];
#pragma unroll
        for (int j = 0; j < 16; ++j)
          ah[j] += a * qs[dd * PIT + th * 16 + j];   // t=31 pad is zero
      }
      float res[16];
#pragma unroll
      for (int j = 0; j < 16; ++j)
        res[j] = gm * ah[j] + qs[c * PIT + th * 16 + j];
      __syncthreads();
#pragma unroll
      for (int j = 0; j < 16; ++j)
        qs[c * PIT + th * 16 + j] = res[j];   // overwrite slice with result
    }
    __syncthreads();
  }

  // coalesced store-out (skips t=31 pad)
  for (int e = tid; e < 8 * 992; e += 128) {
    int xi = e & 7;
    int ct = e >> 3;
    int c = ct / 31;
    int t = ct - c * 31;
    out[((b * HID_ + c) * T_ + t) * SP_ + y * W_ + x0 + xi] =
        qh_s[xi * PSTRIDE + c * PIT + t];
  }
}

// ---------------------------------------------------------------------------
extern "C" void kernel_launch(void* const* d_in, const int* in_sizes, int n_in,
                              void* d_out, int out_size, void* d_ws,
                              size_t ws_size, hipStream_t stream) {
  const float* in    = (const float*)d_in[0];  // [4,32,31,96,96]
  const float* w     = (const float*)d_in[1];  // [64,32,3,3,3]
  const float* bias  = (const float*)d_in[2];  // [64]
  const float* gamma = (const float*)d_in[3];  // [1]
  float* out = (float*)d_out;                  // [4,32,31,96,96]
  float* wr = (float*)d_ws;                    // 221 KB reordered weights

  reorder_w_kernel<<<(8 * NTAP_ * CIN_ * 8 + 255) / 256, 256, 0, stream>>>(w, wr);
  conv_rec_kernel<<<dim3(72, 8, 4), NTHR, 0, stream>>>(in, wr, bias, out);
  attn_kernel<<<dim3(12, 96, 4), 128, 0, stream>>>(out, gamma);
}

// Round 2
// 1233.750 us; speedup vs baseline: 5.4889x; 5.4889x over previous
//
#include <hip/hip_runtime.h>
#include <math.h>

#define B_ 4
#define CIN_ 32
#define HID_ 32
#define T_ 31
#define H_ 96
#define W_ 96
#define SP_ (H_*W_)

typedef _Float16 half8 __attribute__((ext_vector_type(8)));
typedef float f32x4 __attribute__((ext_vector_type(4)));

// ---------------------------------------------------------------------------
// Kernel 0: weights fp32 -> fp16 MFMA A-fragment layout.
// wr[((g*2 + oct)*27 + tap)*512 + lane*8 + i]
//   A[m][k] for mfma_f32_16x16x32_f16: m = lane&15, k = (lane>>4)*8 + i
//   oct=0 -> Z channels oc = g*16 + m ; oct=1 -> F channels oc = 32 + g*16 + m
// ---------------------------------------------------------------------------
__global__ __launch_bounds__(256) void prep_w_kernel(
    const float* __restrict__ w, _Float16* __restrict__ wr) {
  int idx = blockIdx.x * 256 + threadIdx.x;
  if (idx >= 55296) return;
  int i = idx & 7;
  int lane = (idx >> 3) & 63;
  int t27 = idx >> 9;            // (g*2+oct)*27 + tap
  int tap = t27 % 27;
  int q = t27 / 27;
  int oct = q & 1;
  int g = q >> 1;
  int m = lane & 15;
  int kq = lane >> 4;
  int cin = kq * 8 + i;
  int oc = (oct ? 32 : 0) + g * 16 + m;
  wr[idx] = (_Float16)(w[(oc * CIN_ + cin) * 27 + tap]);
}

// ---------------------------------------------------------------------------
// Kernel 1: fused Conv3d (fp16 MFMA implicit GEMM) + gating + time recurrence.
// Block = 256 thr (4 waves). Tile = 16x4 pixels, 32 oc (16 Z + 16 F partners).
// Wave w owns row y0+w: 16 px x 32 oc = 2 MFMA acc frags; 27 taps x 2 MFMA/t.
// Input ring: 3 slices [6 rows][18 cols][32 cin] fp16, pixel pitch 40 f16
// (80 B: 16B-aligned b128 reads, bank stride 20 dw -> 2-way = free).
// Weights staged once: 27648 f16 = 54 KB, lane-linear frag reads.
// ---------------------------------------------------------------------------
#define PITCH 40
#define SLICE_HF (108 * PITCH)   // 4320 f16 per slice

__global__ __launch_bounds__(256) void conv_rec_mfma(
    const float* __restrict__ in, const _Float16* __restrict__ wr,
    const float* __restrict__ bias, float* __restrict__ out) {
  __shared__ _Float16 w_s[27648];            // 55296 B
  __shared__ _Float16 in_s[3 * SLICE_HF];    // 25920 B

  const int tid = threadIdx.x;
  const int tile = blockIdx.x;   // 0..143
  const int g = blockIdx.y;      // 0..1
  const int b = blockIdx.z;      // 0..3
  const int x0 = (tile % 6) * 16;
  const int y0 = (tile / 6) * 4;

  // stage this group's weight fragments (linear copy, conflict-free)
  {
    const float4* src = (const float4*)(wr + g * 27648);
    float4* dst = (float4*)w_s;
    for (int e = tid; e < 3456; e += 256) dst[e] = src[e];
  }

  auto stage = [&](int ts, int slot) {
    _Float16* dstp = in_s + slot * SLICE_HF;
    for (int e = tid; e < 3456; e += 256) {   // 32 cin * 6 rows * 18 cols
      int xx = e % 18;
      int r = e / 18;
      int yy = r % 6;
      int cin = r / 6;
      int gy = y0 - 1 + yy;
      int gx = x0 - 1 + xx;
      float v = 0.f;
      if ((unsigned)ts < (unsigned)T_ && (unsigned)gy < (unsigned)H_ &&
          (unsigned)gx < (unsigned)W_)
        v = in[((b * CIN_ + cin) * T_ + ts) * SP_ + gy * W_ + gx];
      dstp[(yy * 18 + xx) * PITCH + cin] = (_Float16)v;
    }
  };

  const int lane = tid & 63;
  const int w = tid >> 6;        // wave id = row within tile
  const int px = lane & 15;
  const int kq = lane >> 4;

  float bz[4], bf_[4];
#pragma unroll
  for (int j = 0; j < 4; ++j) {
    int m = kq * 4 + j;
    bz[j] = bias[g * 16 + m];
    bf_[j] = bias[32 + g * 16 + m];
  }

  stage(-1, 2);   // zeros
  stage(0, 0);

  float h4[4] = {0.f, 0.f, 0.f, 0.f};

  for (int t = 0; t < T_; ++t) {
    stage(t + 1, (t + 1) % 3);   // zeros when t+1 == 31
    __syncthreads();

    f32x4 acc0 = {0.f, 0.f, 0.f, 0.f};
    f32x4 acc1 = {0.f, 0.f, 0.f, 0.f};

#pragma unroll
    for (int kd = 0; kd < 3; ++kd) {
      const int slot = (t + 2 + kd) % 3;     // slice t-1+kd
      const _Float16* sb = in_s + slot * SLICE_HF;
#pragma unroll
      for (int kh = 0; kh < 3; ++kh) {
        const _Float16* rowp = sb + ((w + kh) * 18 + px) * PITCH + kq * 8;
#pragma unroll
        for (int kw = 0; kw < 3; ++kw) {
          half8 bfrag = *(const half8*)(rowp + kw * PITCH);
          const int tap = kd * 9 + kh * 3 + kw;
          half8 a0 = *(const half8*)(w_s + tap * 512 + lane * 8);
          half8 a1 = *(const half8*)(w_s + (27 + tap) * 512 + lane * 8);
          acc0 = __builtin_amdgcn_mfma_f32_16x16x32_f16(a0, bfrag, acc0, 0, 0, 0);
          acc1 = __builtin_amdgcn_mfma_f32_16x16x32_f16(a1, bfrag, acc1, 0, 0, 0);
        }
      }
    }

    // gating + recurrence; lane holds pixel px, channels c = g*16 + kq*4 + j
#pragma unroll
    for (int j = 0; j < 4; ++j) {
      float zz = tanhf(acc0[j] + bz[j]);
      float ff = 1.f / (1.f + __expf(-(acc1[j] + bf_[j])));
      h4[j] = ff * h4[j] + (1.f - ff) * zz;
      int c = g * 16 + kq * 4 + j;
      out[((b * HID_ + c) * T_ + t) * SP_ + (y0 + w) * W_ + x0 + px] = h4[j];
    }
    __syncthreads();   // ring slot reuse barrier
  }
}

// ---------------------------------------------------------------------------
// Kernel 2: per-pixel channel attention, in-place on d_out (unchanged).
// ---------------------------------------------------------------------------
#define PIT 33
#define PSTRIDE 1089   // 33*33

__global__ __launch_bounds__(128) void attn_kernel(
    float* __restrict__ out, const float* __restrict__ gamma) {
  __shared__ float qh_s[8 * PSTRIDE];       // 34.8 KB
  __shared__ float attn_s[2 * 32 * PIT];    // 8.4 KB

  const int tid = threadIdx.x;
  const int x0 = blockIdx.x * 8;
  const int y = blockIdx.y;
  const int b = blockIdx.z;

  for (int e = tid; e < 8 * 1024; e += 128) {
    int xi = e & 7;
    int ct = e >> 3;
    int t = ct & 31;
    int c = ct >> 5;
    float v = 0.f;
    if (t < T_)
      v = out[((b * HID_ + c) * T_ + t) * SP_ + y * W_ + x0 + xi];
    qh_s[xi * PSTRIDE + c * PIT + t] = v;
  }
  __syncthreads();

  const int wv = tid >> 6;
  const int lane = tid & 63;
  const float gm = gamma[0];

  for (int pp = 0; pp < 4; ++pp) {
    const int p = wv * 4 + pp;
    float* qs = qh_s + p * PSTRIDE;
    float* as = attn_s + wv * (32 * PIT);

    {  // scores + softmax(axis=c) ; lane = (d = lane&31, chalf = lane>>5)
      const int d = lane & 31;
      const int ch = lane >> 5;
      float qd[T_];
#pragma unroll
      for (int t = 0; t < T_; ++t) qd[t] = qs[d * PIT + t];
      float s[16];
#pragma unroll
      for (int i = 0; i < 16; ++i) s[i] = 0.f;
#pragma unroll
      for (int t = 0; t < T_; ++t) {
#pragma unroll
        for (int i = 0; i < 16; ++i)
          s[i] += qs[(ch * 16 + i) * PIT + t] * qd[t];
      }
      float m = s[0];
#pragma unroll
      for (int i = 1; i < 16; ++i) m = fmaxf(m, s[i]);
      m = fmaxf(m, __shfl_xor(m, 32));
      float sum = 0.f;
#pragma unroll
      for (int i = 0; i < 16; ++i) { s[i] = __expf(s[i] - m); sum += s[i]; }
      sum += __shfl_xor(sum, 32);
      const float sc = 0.17677669529663688f / sum;  // (1/sqrt(32)) / denom
#pragma unroll
      for (int i = 0; i < 16; ++i) as[(ch * 16 + i) * PIT + d] = s[i] * sc;
    }
    __syncthreads();
    {  // ah = attn @ qh ; lane = (c = lane&31, thalf = lane>>5)
      const int c = lane & 31;
      const int th = lane >> 5;
      float ah[16];
#pragma unroll
      for (int j = 0; j < 16; ++j) ah[j] = 0.f;
#pragma unroll
      for (int dd = 0; dd < 32; ++dd) {
        float a = as[c * PIT + dd];
#pragma unroll
        for (int j = 0; j < 16; ++j)
          ah[j] += a * qs[dd * PIT + th * 16 + j];
      }
      float res[16];
#pragma unroll
      for (int j = 0; j < 16; ++j)
        res[j] = gm * ah[j] + qs[c * PIT + th * 16 + j];
      __syncthreads();
#pragma unroll
      for (int j = 0; j < 16; ++j)
        qs[c * PIT + th * 16 + j] = res[j];
    }
    __syncthreads();
  }

  for (int e = tid; e < 8 * 992; e += 128) {
    int xi = e & 7;
    int ct = e >> 3;
    int c = ct / 31;
    int t = ct - c * 31;
    out[((b * HID_ + c) * T_ + t) * SP_ + y * W_ + x0 + xi] =
        qh_s[xi * PSTRIDE + c * PIT + t];
  }
}

// ---------------------------------------------------------------------------
extern "C" void kernel_launch(void* const* d_in, const int* in_sizes, int n_in,
                              void* d_out, int out_size, void* d_ws,
                              size_t ws_size, hipStream_t stream) {
  const float* in    = (const float*)d_in[0];  // [4,32,31,96,96]
  const float* w     = (const float*)d_in[1];  // [64,32,3,3,3]
  const float* bias  = (const float*)d_in[2];  // [64]
  const float* gamma = (const float*)d_in[3];  // [1]
  float* out = (float*)d_out;                  // [4,32,31,96,96]
  _Float16* wr = (_Float16*)d_ws;              // 110 KB fp16 fragments

  prep_w_kernel<<<216, 256, 0, stream>>>(w, wr);
  conv_rec_mfma<<<dim3(144, 2, 4), 256, 0, stream>>>(in, wr, bias, out);
  attn_kernel<<<dim3(12, 96, 4), 128, 0, stream>>>(out, gamma);
}